// Round 1
// baseline (530.685 us; speedup 1.0000x reference)
//
#include <hip/hip_runtime.h>

// ONINorm: per-group (g=8, c=32) whitening via Newton-Schulz inverse sqrt.
// Input (262144, 256) fp32. reshape(8,-1,32): group g = contiguous 32MB slab,
// samples = consecutive 32-float chunks.
//
// k1: one-pass Gram + sum per group (per-block partials, deterministic, no atomics)
// k2: reduce partials, S = Gram - n*mu*mu^T + eps*I, Frobenius-normalize,
//     5x Newton-Schulz on 32x32 in LDS, emit M^T = (B/sqrt(normS))^T and bias = M*mu
// k3: out = M*z - bias, tiled, coalesced

#define ROWS 262144
#define COLS 256
#define NG 8
#define NC 32
#define SPG 262144            // samples per group
#define K1_BLOCKS 1024
#define K1_BPG 128            // blocks per group
#define K1_SAMPLES 2048       // samples per block
#define K1_TILES 32
#define K3_BLOCKS 2048
#define K3_BPG 256
#define K3_SAMPLES 1024
#define K3_TILES 16
#define TILE 64               // samples per LDS tile
#define PSTRIDE 1056          // 1024 gram + 32 sums
#define ZSTRIDE 40            // padded sample stride in LDS (16B aligned, bank-rotating)

__global__ __launch_bounds__(256) void k1_stats(const float* __restrict__ x,
                                                float* __restrict__ part) {
  __shared__ __align__(16) float zt[TILE * ZSTRIDE];
  __shared__ __align__(16) float red[4 * PSTRIDE];
  const int t = threadIdx.x;
  const int b = blockIdx.x;
  const int g = b >> 7, lb = b & 127;
  const int w = t >> 6, l = t & 63;
  const int li = l >> 3, lj = l & 7;

  float a00=0,a01=0,a02=0,a03=0;
  float a10=0,a11=0,a12=0,a13=0;
  float a20=0,a21=0,a22=0,a23=0;
  float a30=0,a31=0,a32=0,a33=0;
  float sm0=0,sm1=0,sm2=0,sm3=0;

  const float* gb = x + ((size_t)g * SPG + (size_t)lb * K1_SAMPLES) * NC;
  const int si0 = t >> 3, q0 = t & 7;
  const int si1 = (t + 256) >> 3, q1 = (t + 256) & 7;

  for (int tile = 0; tile < K1_TILES; ++tile) {
    const float* tb = gb + (size_t)tile * (TILE * NC);
    float4 v0 = *(const float4*)(tb + t * 4);
    float4 v1 = *(const float4*)(tb + (t + 256) * 4);
    __syncthreads();  // previous tile's compute done reading zt
    *(float4*)&zt[si0 * ZSTRIDE + q0 * 4] = v0;
    *(float4*)&zt[si1 * ZSTRIDE + q1 * 4] = v1;
    __syncthreads();
#pragma unroll
    for (int it = 0; it < 16; ++it) {
      const float* zp = &zt[(w * 16 + it) * ZSTRIDE];
      float4 zr = *(const float4*)(zp + li * 4);
      float4 zc = *(const float4*)(zp + lj * 4);
      a00 += zr.x*zc.x; a01 += zr.x*zc.y; a02 += zr.x*zc.z; a03 += zr.x*zc.w;
      a10 += zr.y*zc.x; a11 += zr.y*zc.y; a12 += zr.y*zc.z; a13 += zr.y*zc.w;
      a20 += zr.z*zc.x; a21 += zr.z*zc.y; a22 += zr.z*zc.z; a23 += zr.z*zc.w;
      a30 += zr.w*zc.x; a31 += zr.w*zc.y; a32 += zr.w*zc.z; a33 += zr.w*zc.w;
      sm0 += zr.x; sm1 += zr.y; sm2 += zr.z; sm3 += zr.w;
    }
  }
  __syncthreads();
  float* rw = &red[w * PSTRIDE];
  *(float4*)&rw[(li*4+0)*32 + lj*4] = make_float4(a00,a01,a02,a03);
  *(float4*)&rw[(li*4+1)*32 + lj*4] = make_float4(a10,a11,a12,a13);
  *(float4*)&rw[(li*4+2)*32 + lj*4] = make_float4(a20,a21,a22,a23);
  *(float4*)&rw[(li*4+3)*32 + lj*4] = make_float4(a30,a31,a32,a33);
  if (lj == 0) *(float4*)&rw[1024 + li*4] = make_float4(sm0,sm1,sm2,sm3);
  __syncthreads();
  float* po = part + (size_t)b * PSTRIDE;
  for (int e = t; e < PSTRIDE; e += 256)
    po[e] = red[e] + red[PSTRIDE+e] + red[2*PSTRIDE+e] + red[3*PSTRIDE+e];
}

__global__ __launch_bounds__(1024) void k2_solve(const float* __restrict__ part,
                                                 float* __restrict__ mt,
                                                 float* __restrict__ bias) {
  __shared__ float S[NC][NC+1], Bm[NC][NC+1], T1[NC][NC+1], T2[NC][NC+1];
  __shared__ float mu[NC];
  __shared__ float red[1024];
  const int g = blockIdx.x;
  const int t = threadIdx.x;
  const int c = t >> 5, d = t & 31;
  const float* pb = part + (size_t)g * K1_BPG * PSTRIDE;

  float gs = 0.f;
  for (int b = 0; b < K1_BPG; ++b) gs += pb[(size_t)b * PSTRIDE + t];
  if (t < NC) {
    float cs = 0.f;
    for (int b = 0; b < K1_BPG; ++b) cs += pb[(size_t)b * PSTRIDE + 1024 + t];
    mu[t] = cs * (1.f / (float)SPG);
  }
  __syncthreads();

  float Sv = gs - (float)SPG * mu[c] * mu[d] + ((c == d) ? 1e-5f : 0.f);
  red[t] = Sv * Sv;
  __syncthreads();
  for (int off = 512; off > 0; off >>= 1) {
    if (t < off) red[t] += red[t + off];
    __syncthreads();
  }
  const float normS = sqrtf(red[0]);
  S[c][d] = Sv * (1.f / normS);
  Bm[c][d] = (c == d) ? 1.f : 0.f;
  __syncthreads();

  for (int it = 0; it < 5; ++it) {
    float a = 0.f;
#pragma unroll
    for (int k = 0; k < NC; ++k) a += Bm[c][k] * Bm[k][d];
    T1[c][d] = a;
    __syncthreads();
    float b2 = 0.f;
#pragma unroll
    for (int k = 0; k < NC; ++k) b2 += T1[c][k] * Bm[k][d];
    T2[c][d] = b2;
    __syncthreads();
    float c3 = 0.f;
#pragma unroll
    for (int k = 0; k < NC; ++k) c3 += T2[c][k] * S[k][d];
    float nb = 1.5f * Bm[c][d] - 0.5f * c3;
    __syncthreads();
    Bm[c][d] = nb;
    __syncthreads();
  }

  const float Mv = Bm[c][d] * (1.f / sqrtf(normS));
  mt[g * 1024 + d * 32 + c] = Mv;  // transposed for k3's read pattern
  red[t] = Mv * mu[d];
  __syncthreads();
  for (int off = 16; off > 0; off >>= 1) {
    if (d < off) red[t] += red[t + off];
    __syncthreads();
  }
  if (d == 0) bias[g * 32 + c] = red[t];
}

__global__ __launch_bounds__(256) void k3_apply(const float* __restrict__ x,
                                                const float* __restrict__ mt,
                                                const float* __restrict__ bias,
                                                float* __restrict__ out) {
  __shared__ __align__(16) float Mt[1024];
  __shared__ __align__(16) float zt[TILE * ZSTRIDE];
  const int t = threadIdx.x;
  const int b = blockIdx.x;
  const int g = b >> 8, lb = b & 255;
  const int k = t & 7, sl = t >> 3;

  *(float4*)&Mt[t * 4] = *(const float4*)&mt[g * 1024 + t * 4];
  float4 bi = *(const float4*)&bias[g * 32 + k * 4];
  const size_t base = ((size_t)g * SPG + (size_t)lb * K3_SAMPLES) * NC;
  const int si0 = t >> 3, q0 = t & 7;
  const int si1 = (t + 256) >> 3, q1 = (t + 256) & 7;

  for (int tile = 0; tile < K3_TILES; ++tile) {
    const float* tb = x + base + (size_t)tile * (TILE * NC);
    float4 v0 = *(const float4*)(tb + t * 4);
    float4 v1 = *(const float4*)(tb + (t + 256) * 4);
    __syncthreads();  // prior compute done reading zt (also covers Mt load on tile 0)
    *(float4*)&zt[si0 * ZSTRIDE + q0 * 4] = v0;
    *(float4*)&zt[si1 * ZSTRIDE + q1 * 4] = v1;
    __syncthreads();

    float acc0[4] = {0,0,0,0}, acc1[4] = {0,0,0,0};
    const float* z0 = &zt[sl * ZSTRIDE];
    const float* z1 = &zt[(sl + 32) * ZSTRIDE];
#pragma unroll
    for (int dq = 0; dq < 8; ++dq) {
      float4 za4 = *(const float4*)(z0 + dq * 4);
      float4 zb4 = *(const float4*)(z1 + dq * 4);
      const float* za = (const float*)&za4;
      const float* zb = (const float*)&zb4;
#pragma unroll
      for (int dd = 0; dd < 4; ++dd) {
        float4 m4 = *(const float4*)&Mt[(dq * 4 + dd) * 32 + k * 4];
        acc0[0] += m4.x * za[dd]; acc0[1] += m4.y * za[dd];
        acc0[2] += m4.z * za[dd]; acc0[3] += m4.w * za[dd];
        acc1[0] += m4.x * zb[dd]; acc1[1] += m4.y * zb[dd];
        acc1[2] += m4.z * zb[dd]; acc1[3] += m4.w * zb[dd];
      }
    }
    float* ob = out + base + (size_t)tile * (TILE * NC);
    *(float4*)(ob + sl * 32 + k * 4) =
        make_float4(acc0[0]-bi.x, acc0[1]-bi.y, acc0[2]-bi.z, acc0[3]-bi.w);
    *(float4*)(ob + (sl + 32) * 32 + k * 4) =
        make_float4(acc1[0]-bi.x, acc1[1]-bi.y, acc1[2]-bi.z, acc1[3]-bi.w);
  }
}

extern "C" void kernel_launch(void* const* d_in, const int* in_sizes, int n_in,
                              void* d_out, int out_size, void* d_ws, size_t ws_size,
                              hipStream_t stream) {
  (void)in_sizes; (void)n_in; (void)out_size; (void)ws_size;
  const float* x = (const float*)d_in[0];
  float* out = (float*)d_out;
  float* ws = (float*)d_ws;
  float* part = ws;                                        // 1024 * 1056 floats
  float* mt   = ws + (size_t)K1_BLOCKS * PSTRIDE;          // 8 * 1024 floats
  float* bias = mt + NG * 1024;                            // 8 * 32 floats

  k1_stats<<<K1_BLOCKS, 256, 0, stream>>>(x, part);
  k2_solve<<<NG, 1024, 0, stream>>>(part, mt, bias);
  k3_apply<<<K3_BLOCKS, 256, 0, stream>>>(x, mt, bias, out);
}